// Round 11
// baseline (151.844 us; speedup 1.0000x reference)
//
#include <hip/hip_runtime.h>
#include <hip/hip_bf16.h>
#include <math.h>

using bf16 = __hip_bfloat16;
typedef __attribute__((ext_vector_type(8))) short short8;
typedef __attribute__((ext_vector_type(4))) short short4_;
typedef __attribute__((ext_vector_type(4))) float floatx4;

#define C_DIM   512
#define N_TOK   1024
#define NHEAD   8
#define HDIM    64
#define LN_EPSF 1e-5f

// RNE float -> bf16 bits
__device__ __forceinline__ unsigned short f2b(float f) {
    union { float f; unsigned int u; } v; v.f = f;
    unsigned int r = v.u + 0x7FFFu + ((v.u >> 16) & 1u);
    return (unsigned short)(r >> 16);
}
__device__ __forceinline__ float b2f(unsigned short u) {
    union { unsigned int i; float f; } v; v.i = ((unsigned int)u) << 16; return v.f;
}

// ------ Kernel 1: fused LN(stats+normalize)->frag-order | sincos | w->frag-order ------
// blocks [0,128): per-64-token LN stats (LDS-resident) + normalize + A-frag store:
//   xnf[g16(512)][ks(16)][lane(64)][8] = xn[g16*16+c][ks*32+quad*8+j]  (lane=quad*16+c)
// blocks [128,256): rope table sc[n][32] float2(sin,cos)
// blocks [256,640): w fp32 -> B-frag order wf[j16(96)][ks(16)][lane][8]
__global__ __launch_bounds__(256) void prep_kernel(
        const float* __restrict__ x, const float* __restrict__ w,
        const float* __restrict__ gamma, const float* __restrict__ beta,
        float* __restrict__ sc, unsigned short* __restrict__ xnf,
        unsigned short* __restrict__ wf) {
    const int bx = blockIdx.x;
    const int t  = threadIdx.x;
    if (bx < 128) {
        __shared__ float red_s[4][64];
        __shared__ float red_q[4][64];
        __shared__ float lmu[64];
        __shared__ float lrs[64];
        __shared__ short Sx[64][72];
        const int b  = bx >> 4;
        const int n0 = (bx & 15) * 64;
        // ---- stats pass (x read once per element; chunk pass below hits L1/L2) ----
        {
            const int rl = t & 63;
            const int cg = t >> 6;
            const float* xp = x + (size_t)b * C_DIM * N_TOK + n0 + rl;
            float s = 0.f, q = 0.f;
            #pragma unroll 4
            for (int i = 0; i < 128; ++i) {
                float v = xp[(size_t)(cg * 128 + i) * N_TOK];
                s += v; q += v * v;
            }
            red_s[cg][rl] = s; red_q[cg][rl] = q;
            __syncthreads();
            if (cg == 0) {
                float S = red_s[0][rl] + red_s[1][rl] + red_s[2][rl] + red_s[3][rl];
                float Q = red_q[0][rl] + red_q[1][rl] + red_q[2][rl] + red_q[3][rl];
                float m   = S * (1.0f / C_DIM);
                float var = Q * (1.0f / C_DIM) - m * m;
                lmu[rl] = m;
                lrs[rl] = rsqrtf(var + LN_EPSF);
            }
            __syncthreads();
        }
        // ---- normalize + transpose to frag order, 64-channel chunks ----
        const int nq  = t & 15;
        const int crl = t >> 4;
        const int wv   = t >> 6;
        const int lane = t & 63;
        const int cfr  = lane & 15;
        const int quad = lane >> 4;
        const int g16  = b * 64 + (n0 >> 4) + wv;
        const float4 m4 = *(const float4*)&lmu[nq * 4];
        const float4 r4 = *(const float4*)&lrs[nq * 4];
        for (int cc = 0; cc < 8; ++cc) {
            const int c0 = cc * 64;
            #pragma unroll
            for (int p = 0; p < 4; ++p) {
                const int c = c0 + p * 16 + crl;
                const float g = gamma[c], bt = beta[c];
                const float4 xv = *(const float4*)(x + (size_t)b * C_DIM * N_TOK + (size_t)c * N_TOK + n0 + nq * 4);
                Sx[nq * 4 + 0][p * 16 + crl] = (short)f2b((xv.x - m4.x) * r4.x * g + bt);
                Sx[nq * 4 + 1][p * 16 + crl] = (short)f2b((xv.y - m4.y) * r4.y * g + bt);
                Sx[nq * 4 + 2][p * 16 + crl] = (short)f2b((xv.z - m4.z) * r4.z * g + bt);
                Sx[nq * 4 + 3][p * 16 + crl] = (short)f2b((xv.w - m4.w) * r4.w * g + bt);
            }
            __syncthreads();
            #pragma unroll
            for (int ks = 0; ks < 2; ++ks) {
                short8 v = *(const short8*)&Sx[wv * 16 + cfr][ks * 32 + quad * 8];
                *(short8*)(xnf + (((size_t)g16 * 16 + cc * 2 + ks) * 64 + lane) * 8) = v;
            }
            __syncthreads();
        }
    } else if (bx < 256) {
        const int idx = (bx - 128) * 256 + t;      // n*32 + f
        const int n = idx >> 5, f = idx & 31;
        const float fr = __expf((float)f * (-9.210340371976184f / 32.0f));
        float sv, cv;
        sincosf((float)n * fr, &sv, &cv);
        ((float2*)sc)[idx] = make_float2(sv, cv);
    } else {
        const int id   = (bx - 256) * 256 + t;     // chunk id in [0, 96*16*64)
        const int lane = id & 63;
        const int ksl  = (id >> 6) & 15;
        const int j16  = id >> 10;
        const int c    = lane & 15;
        const int quad = lane >> 4;
        const float* wp = w + (size_t)(j16 * 16 + c) * C_DIM + ksl * 32 + quad * 8;
        const float4 w0 = *(const float4*)(wp);
        const float4 w1 = *(const float4*)(wp + 4);
        short8 pk;
        pk[0] = (short)f2b(w0.x); pk[1] = (short)f2b(w0.y);
        pk[2] = (short)f2b(w0.z); pk[3] = (short)f2b(w0.w);
        pk[4] = (short)f2b(w1.x); pk[5] = (short)f2b(w1.y);
        pk[6] = (short)f2b(w1.z); pk[7] = (short)f2b(w1.w);
        *(short8*)(wf + (size_t)id * 8) = pk;
    }
}

// ---------------- Kernel 2: QKV MFMA GEMM + bias + RoPE + fragment-order scatter -------
__global__ __launch_bounds__(256) void qkv_mfma_kernel(
        const unsigned short* __restrict__ xnf, const unsigned short* __restrict__ wf,
        const float* __restrict__ bias, const float* __restrict__ sc,
        unsigned short* __restrict__ qfr, unsigned short* __restrict__ kfr,
        unsigned short* __restrict__ vfr) {
    __shared__ short Es[4][64][72];

    const int t    = threadIdx.x;
    const int wv   = t >> 6;
    const int lane = t & 63;
    const int cl   = lane & 15;
    const int quad = lane >> 4;
    const int t0   = blockIdx.x * 128 + (wv & 1) * 64;
    const int j0w  = blockIdx.y * 128 + (wv >> 1) * 64;
    const int which = j0w >> 9;                 // 0=q 1=k 2=v
    const int h     = (j0w >> 6) & 7;
    const int b     = t0 >> 10;
    const int n0q   = t0 & 1023;
    const int bh    = b * NHEAD + h;

    const unsigned short* ap = xnf + (size_t)(t0 >> 4) * 8192 + lane * 8;
    const unsigned short* bp = wf  + (size_t)(j0w >> 4) * 8192 + lane * 8;

    floatx4 acc[4][4];
    #pragma unroll
    for (int i = 0; i < 4; ++i)
        #pragma unroll
        for (int j = 0; j < 4; ++j) acc[i][j] = (floatx4){0.f, 0.f, 0.f, 0.f};

    #pragma unroll 2
    for (int kt = 0; kt < 16; ++kt) {
        short8 af[4], bfr[4];
        #pragma unroll
        for (int tt = 0; tt < 4; ++tt) af[tt]  = *(const short8*)(ap + ((size_t)tt * 16 + kt) * 512);
        #pragma unroll
        for (int jt = 0; jt < 4; ++jt) bfr[jt] = *(const short8*)(bp + ((size_t)jt * 16 + kt) * 512);
        #pragma unroll
        for (int tt = 0; tt < 4; ++tt)
            #pragma unroll
            for (int jt = 0; jt < 4; ++jt)
                acc[tt][jt] = __builtin_amdgcn_mfma_f32_16x16x32_bf16(af[tt], bfr[jt], acc[tt][jt], 0, 0, 0);
    }

    float bj[4];
    #pragma unroll
    for (int jt = 0; jt < 4; ++jt) bj[jt] = bias[j0w + jt * 16 + cl];
    #pragma unroll
    for (int tt = 0; tt < 4; ++tt)
        #pragma unroll
        for (int jt = 0; jt < 4; ++jt)
            #pragma unroll
            for (int r = 0; r < 4; ++r)
                Es[wv][tt * 16 + quad * 4 + r][jt * 16 + cl] = (short)f2b(acc[tt][jt][r] + bj[jt]);
    // same-wave LDS read-after-write: ordered by lgkmcnt (no barrier needed)

    if (which == 2) {
        unsigned short* vfb = vfr + ((size_t)bh * 16 + (n0q >> 6)) * 4096;
        #pragma unroll
        for (int dt = 0; dt < 4; ++dt) {
            #pragma unroll
            for (int ks = 0; ks < 2; ++ks) {
                short8 pk;
                #pragma unroll
                for (int j = 0; j < 8; ++j)
                    pk[j] = Es[wv][ks * 32 + quad * 8 + j][dt * 16 + cl];
                *(short8*)(vfb + (((size_t)dt * 2 + ks) * 64 + lane) * 8) = pk;
            }
        }
    } else {
        const float oscale = (which == 0) ? 0.125f : 1.0f;
        unsigned short* base = (which == 0)
            ? qfr + ((size_t)bh * 64 + (n0q >> 4)) * 1024
            : kfr + ((size_t)bh * 16 + (n0q >> 6)) * 4096;
        #pragma unroll
        for (int mt = 0; mt < 4; ++mt) {
            const int n = n0q + mt * 16 + cl;
            const float* scp = sc + ((size_t)n * 32 + quad * 4) * 2;
            #pragma unroll
            for (int ks = 0; ks < 2; ++ks) {
                const short8 v8 = *(const short8*)&Es[wv][mt * 16 + cl][ks * 32 + quad * 8];
                const short8 p8 = *(const short8*)&Es[wv][mt * 16 + cl][(ks ^ 1) * 32 + quad * 8];
                const float* sp = scp + ks * 32;               // f = ks*16 + quad*4
                const float4 s0 = *(const float4*)sp;
                const float4 s1 = *(const float4*)(sp + 4);
                const float sv[4] = {s0.x, s0.z, s1.x, s1.z};
                const float cv[4] = {s0.y, s0.w, s1.y, s1.w};
                const float sgn = ks ? 1.0f : -1.0f;           // d<32 <=> ks==0
                short8 pk;
                #pragma unroll
                for (int j = 0; j < 8; ++j) {
                    const int f = j >> 1;
                    const float val = b2f((unsigned short)v8[j]);
                    const float par = b2f((unsigned short)p8[j]);
                    pk[j] = (short)f2b((val * cv[f] + sgn * par * sv[f]) * oscale);
                }
                *(short8*)(base + (((size_t)mt * 2 + ks) * 64 + lane) * 8) = pk;
            }
        }
    }
}

// ---------------- Kernel 3: MFMA flash attention, 32 q/wave, 3 waves/SIMD -------------
// 1 wave/block, 32 q-rows (2 qt chains), fragment-order single-segment loads,
// fixed-shift softmax. 32q halves per-wave K/V L2 traffic vs 16q (1 GB -> 512 MB).
__global__ __launch_bounds__(64, 3) void attn_mfma_kernel(
        const unsigned short* __restrict__ qfr, const unsigned short* __restrict__ kfr,
        const unsigned short* __restrict__ vfr, float* __restrict__ out) {
    __shared__ __align__(16) short Plds[2][16][72];   // [qt][q=c][key]

    const int lane = threadIdx.x;
    const int c    = lane & 15;
    const int quad = lane >> 4;
    const int i    = blockIdx.x;
    const int bh   = (i & 7) * 8 + ((i >> 3) & 7);   // XCD swizzle: 8 bh per XCD
    const int q32  = i >> 6;                         // q-tile of 32 rows, [0,32)
    const int b    = bh >> 3, h = bh & 7;

    const unsigned short* qp = qfr + ((size_t)bh * 64 + q32 * 2) * 1024 + lane * 8;
    const unsigned short* kp = kfr + (size_t)bh * 65536 + lane * 8;
    const unsigned short* vp = vfr + (size_t)bh * 65536 + lane * 8;

    short8 qf[2][2];
    #pragma unroll
    for (int qt = 0; qt < 2; ++qt)
        #pragma unroll
        for (int ks = 0; ks < 2; ++ks)
            qf[qt][ks] = *(const short8*)(qp + ((size_t)qt * 2 + ks) * 512);

    floatx4 o_acc[2][4];
    float l_acc[2] = {0.f, 0.f};
    #pragma unroll
    for (int qt = 0; qt < 2; ++qt)
        #pragma unroll
        for (int dt = 0; dt < 4; ++dt) o_acc[qt][dt] = (floatx4){0.f, 0.f, 0.f, 0.f};

    #pragma unroll 1
    for (int kt = 0; kt < 16; ++kt) {
        const unsigned short* kb = kp + (size_t)kt * 4096;
        const unsigned short* vb = vp + (size_t)kt * 4096;
        short8 kf[4][2], vf[4][2];
        #pragma unroll
        for (int mt = 0; mt < 4; ++mt) {
            #pragma unroll
            for (int ks = 0; ks < 2; ++ks) {
                kf[mt][ks] = *(const short8*)(kb + ((size_t)mt * 2 + ks) * 512);
                vf[mt][ks] = *(const short8*)(vb + ((size_t)mt * 2 + ks) * 512);
            }
        }

        // S^T: rows=keys (mt), col=q=c
        floatx4 st[2][4];
        #pragma unroll
        for (int qt = 0; qt < 2; ++qt) {
            #pragma unroll
            for (int mt = 0; mt < 4; ++mt) {
                floatx4 z = (floatx4){0.f, 0.f, 0.f, 0.f};
                z = __builtin_amdgcn_mfma_f32_16x16x32_bf16(kf[mt][0], qf[qt][0], z, 0, 0, 0);
                st[qt][mt] = __builtin_amdgcn_mfma_f32_16x16x32_bf16(kf[mt][1], qf[qt][1], z, 0, 0, 0);
            }
        }

        // fixed-shift exp (P = exp(S-16), shift-invariant); pack to per-wave LDS
        #pragma unroll
        for (int qt = 0; qt < 2; ++qt) {
            #pragma unroll
            for (int mt = 0; mt < 4; ++mt) {
                const float e0 = __expf(st[qt][mt][0] - 16.0f);
                const float e1 = __expf(st[qt][mt][1] - 16.0f);
                const float e2 = __expf(st[qt][mt][2] - 16.0f);
                const float e3 = __expf(st[qt][mt][3] - 16.0f);
                l_acc[qt] += (e0 + e1) + (e2 + e3);
                short4_ pk;
                pk.x = (short)f2b(e0); pk.y = (short)f2b(e1);
                pk.z = (short)f2b(e2); pk.w = (short)f2b(e3);
                *(short4_*)&Plds[qt][c][mt * 16 + quad * 4] = pk;
            }
        }

        // PV: O^T += V^T . P^T
        #pragma unroll
        for (int qt = 0; qt < 2; ++qt) {
            const short8 pf0 = *(const short8*)&Plds[qt][c][quad * 8];
            const short8 pf1 = *(const short8*)&Plds[qt][c][32 + quad * 8];
            #pragma unroll
            for (int dt = 0; dt < 4; ++dt) {
                o_acc[qt][dt] = __builtin_amdgcn_mfma_f32_16x16x32_bf16(vf[dt][0], pf0, o_acc[qt][dt], 0, 0, 0);
                o_acc[qt][dt] = __builtin_amdgcn_mfma_f32_16x16x32_bf16(vf[dt][1], pf1, o_acc[qt][dt], 0, 0, 0);
            }
        }
    }

    #pragma unroll
    for (int qt = 0; qt < 2; ++qt) {
        float l = l_acc[qt];
        l += __shfl_xor(l, 16);
        l += __shfl_xor(l, 32);
        const float inv = 1.0f / l;
        const int qcol = q32 * 32 + qt * 16 + c;
        #pragma unroll
        for (int dt = 0; dt < 4; ++dt) {
            #pragma unroll
            for (int r = 0; r < 4; ++r) {
                const int d = dt * 16 + quad * 4 + r;
                out[((size_t)b * C_DIM + h * HDIM + d) * N_TOK + qcol] = o_acc[qt][dt][r] * inv;
            }
        }
    }
}

extern "C" void kernel_launch(void* const* d_in, const int* in_sizes, int n_in,
                              void* d_out, int out_size, void* d_ws, size_t ws_size,
                              hipStream_t stream) {
    const float* x     = (const float*)d_in[0];
    const float* w     = (const float*)d_in[1];
    const float* bias  = (const float*)d_in[2];
    const float* gamma = (const float*)d_in[3];
    const float* beta  = (const float*)d_in[4];
    float* out = (float*)d_out;

    char* ws = (char*)d_ws;
    unsigned short* qfr = (unsigned short*)ws;                   // 8 MB
    unsigned short* kfr = (unsigned short*)(ws + 8388608);       // 8 MB
    unsigned short* vfr = (unsigned short*)(ws + 16777216);      // 8 MB
    unsigned short* xnf = (unsigned short*)(ws + 25165824);      // 8 MB
    unsigned short* wf  = (unsigned short*)(ws + 33554432);      // 1.5 MB
    float* sc           = (float*)(ws + 35127296);               // 256 KB

    hipLaunchKernelGGL(prep_kernel, dim3(640), dim3(256), 0, stream,
                       x, w, gamma, beta, sc, xnf, wf);
    hipLaunchKernelGGL(qkv_mfma_kernel, dim3(64, 12), dim3(256), 0, stream,
                       xnf, wf, bias, sc, qfr, kfr, vfr);
    hipLaunchKernelGGL(attn_mfma_kernel, dim3(2048), dim3(64), 0, stream, qfr, kfr, vfr, out);
}

// Round 12
// 151.036 us; speedup vs baseline: 1.0053x; 1.0053x over previous
//
#include <hip/hip_runtime.h>
#include <hip/hip_bf16.h>
#include <math.h>

using bf16 = __hip_bfloat16;
typedef __attribute__((ext_vector_type(8))) short short8;
typedef __attribute__((ext_vector_type(4))) short short4_;
typedef __attribute__((ext_vector_type(4))) float floatx4;

#define C_DIM   512
#define N_TOK   1024
#define NHEAD   8
#define HDIM    64
#define LN_EPSF 1e-5f

// RNE float -> bf16 bits
__device__ __forceinline__ unsigned short f2b(float f) {
    union { float f; unsigned int u; } v; v.f = f;
    unsigned int r = v.u + 0x7FFFu + ((v.u >> 16) & 1u);
    return (unsigned short)(r >> 16);
}
__device__ __forceinline__ float b2f(unsigned short u) {
    union { unsigned int i; float f; } v; v.i = ((unsigned int)u) << 16; return v.f;
}

// ---------------- Kernel 1: prep = LN stats | sincos table | w->frag-order bf16 -------
__global__ __launch_bounds__(256) void prep_kernel(
        const float* __restrict__ x, const float* __restrict__ w,
        float* __restrict__ mu, float* __restrict__ rsig,
        float* __restrict__ sc, unsigned short* __restrict__ wf) {
    __shared__ float red_s[4][64];
    __shared__ float red_q[4][64];
    const int bx = blockIdx.x;
    const int t  = threadIdx.x;
    if (bx < 128) {
        const int rl = t & 63;
        const int cg = t >> 6;
        const int r0 = bx * 64;
        const int b  = r0 >> 10;
        const int n  = (r0 & 1023) + rl;
        const float* xp = x + (size_t)b * C_DIM * N_TOK + n;
        float s = 0.f, q = 0.f;
        #pragma unroll 4
        for (int i = 0; i < 128; ++i) {
            float v = xp[(size_t)(cg * 128 + i) * N_TOK];
            s += v; q += v * v;
        }
        red_s[cg][rl] = s; red_q[cg][rl] = q;
        __syncthreads();
        if (cg == 0) {
            float S = red_s[0][rl] + red_s[1][rl] + red_s[2][rl] + red_s[3][rl];
            float Q = red_q[0][rl] + red_q[1][rl] + red_q[2][rl] + red_q[3][rl];
            float m   = S * (1.0f / C_DIM);
            float var = Q * (1.0f / C_DIM) - m * m;
            mu[r0 + rl]   = m;
            rsig[r0 + rl] = rsqrtf(var + LN_EPSF);
        }
    } else if (bx < 256) {
        const int idx = (bx - 128) * 256 + t;      // n*32 + f
        const int n = idx >> 5, f = idx & 31;
        const float fr = __expf((float)f * (-9.210340371976184f / 32.0f));
        float sv, cv;
        sincosf((float)n * fr, &sv, &cv);
        ((float2*)sc)[idx] = make_float2(sv, cv);
    } else {
        const int id   = (bx - 256) * 256 + t;     // chunk id in [0, 96*16*64)
        const int lane = id & 63;
        const int ksl  = (id >> 6) & 15;
        const int j16  = id >> 10;
        const int c    = lane & 15;
        const int quad = lane >> 4;
        const float* wp = w + (size_t)(j16 * 16 + c) * C_DIM + ksl * 32 + quad * 8;
        const float4 w0 = *(const float4*)(wp);
        const float4 w1 = *(const float4*)(wp + 4);
        short8 pk;
        pk[0] = (short)f2b(w0.x); pk[1] = (short)f2b(w0.y);
        pk[2] = (short)f2b(w0.z); pk[3] = (short)f2b(w0.w);
        pk[4] = (short)f2b(w1.x); pk[5] = (short)f2b(w1.y);
        pk[6] = (short)f2b(w1.z); pk[7] = (short)f2b(w1.w);
        *(short8*)(wf + (size_t)id * 8) = pk;
    }
}

// ---------------- Kernel 2: normalize + transpose -> A-fragment order ----------------
__global__ __launch_bounds__(256) void xnt_kernel(
        const float* __restrict__ x, const float* __restrict__ gamma,
        const float* __restrict__ beta, const float* __restrict__ mu,
        const float* __restrict__ rsig, unsigned short* __restrict__ xnf) {
    __shared__ short Sx[64][72];
    const int t  = threadIdx.x;
    const int c0 = blockIdx.x * 64;
    const int n0 = blockIdx.y * 64;
    const int b  = blockIdx.z;

    const int nq  = t & 15;
    const int crl = t >> 4;
    const int tok = b * N_TOK + n0 + nq * 4;
    const float4 m4 = *(const float4*)(mu + tok);
    const float4 r4 = *(const float4*)(rsig + tok);
    #pragma unroll
    for (int p = 0; p < 4; ++p) {
        const int c = c0 + p * 16 + crl;
        const float g = gamma[c], bt = beta[c];
        const float4 xv = *(const float4*)(x + (size_t)b * C_DIM * N_TOK + (size_t)c * N_TOK + n0 + nq * 4);
        Sx[nq * 4 + 0][p * 16 + crl] = (short)f2b((xv.x - m4.x) * r4.x * g + bt);
        Sx[nq * 4 + 1][p * 16 + crl] = (short)f2b((xv.y - m4.y) * r4.y * g + bt);
        Sx[nq * 4 + 2][p * 16 + crl] = (short)f2b((xv.z - m4.z) * r4.z * g + bt);
        Sx[nq * 4 + 3][p * 16 + crl] = (short)f2b((xv.w - m4.w) * r4.w * g + bt);
    }
    __syncthreads();
    const int wv   = t >> 6;
    const int lane = t & 63;
    const int cfr  = lane & 15;
    const int quad = lane >> 4;
    const int g16  = b * 64 + ((n0 >> 4) + wv);
    #pragma unroll
    for (int ks = 0; ks < 2; ++ks) {
        short8 v = *(const short8*)&Sx[wv * 16 + cfr][ks * 32 + quad * 8];
        *(short8*)(xnf + (((size_t)g16 * 16 + (c0 >> 5) + ks) * 64 + lane) * 8) = v;
    }
}

// ---------------- Kernel 3: QKV MFMA GEMM + bias + RoPE + fragment-order scatter -------
__global__ __launch_bounds__(256) void qkv_mfma_kernel(
        const unsigned short* __restrict__ xnf, const unsigned short* __restrict__ wf,
        const float* __restrict__ bias, const float* __restrict__ sc,
        unsigned short* __restrict__ qfr, unsigned short* __restrict__ kfr,
        unsigned short* __restrict__ vfr) {
    __shared__ short Es[4][64][72];

    const int t    = threadIdx.x;
    const int wv   = t >> 6;
    const int lane = t & 63;
    const int cl   = lane & 15;
    const int quad = lane >> 4;
    const int t0   = blockIdx.x * 128 + (wv & 1) * 64;
    const int j0w  = blockIdx.y * 128 + (wv >> 1) * 64;
    const int which = j0w >> 9;                 // 0=q 1=k 2=v
    const int h     = (j0w >> 6) & 7;
    const int b     = t0 >> 10;
    const int n0q   = t0 & 1023;
    const int bh    = b * NHEAD + h;

    const unsigned short* ap = xnf + (size_t)(t0 >> 4) * 8192 + lane * 8;
    const unsigned short* bp = wf  + (size_t)(j0w >> 4) * 8192 + lane * 8;

    floatx4 acc[4][4];
    #pragma unroll
    for (int i = 0; i < 4; ++i)
        #pragma unroll
        for (int j = 0; j < 4; ++j) acc[i][j] = (floatx4){0.f, 0.f, 0.f, 0.f};

    #pragma unroll 2
    for (int kt = 0; kt < 16; ++kt) {
        short8 af[4], bfr[4];
        #pragma unroll
        for (int tt = 0; tt < 4; ++tt) af[tt]  = *(const short8*)(ap + ((size_t)tt * 16 + kt) * 512);
        #pragma unroll
        for (int jt = 0; jt < 4; ++jt) bfr[jt] = *(const short8*)(bp + ((size_t)jt * 16 + kt) * 512);
        #pragma unroll
        for (int tt = 0; tt < 4; ++tt)
            #pragma unroll
            for (int jt = 0; jt < 4; ++jt)
                acc[tt][jt] = __builtin_amdgcn_mfma_f32_16x16x32_bf16(af[tt], bfr[jt], acc[tt][jt], 0, 0, 0);
    }

    float bj[4];
    #pragma unroll
    for (int jt = 0; jt < 4; ++jt) bj[jt] = bias[j0w + jt * 16 + cl];
    #pragma unroll
    for (int tt = 0; tt < 4; ++tt)
        #pragma unroll
        for (int jt = 0; jt < 4; ++jt)
            #pragma unroll
            for (int r = 0; r < 4; ++r)
                Es[wv][tt * 16 + quad * 4 + r][jt * 16 + cl] = (short)f2b(acc[tt][jt][r] + bj[jt]);
    // same-wave LDS read-after-write: ordered by lgkmcnt (no barrier needed)

    if (which == 2) {
        unsigned short* vfb = vfr + ((size_t)bh * 16 + (n0q >> 6)) * 4096;
        #pragma unroll
        for (int dt = 0; dt < 4; ++dt) {
            #pragma unroll
            for (int ks = 0; ks < 2; ++ks) {
                short8 pk;
                #pragma unroll
                for (int j = 0; j < 8; ++j)
                    pk[j] = Es[wv][ks * 32 + quad * 8 + j][dt * 16 + cl];
                *(short8*)(vfb + (((size_t)dt * 2 + ks) * 64 + lane) * 8) = pk;
            }
        }
    } else {
        const float oscale = (which == 0) ? 0.125f : 1.0f;
        unsigned short* base = (which == 0)
            ? qfr + ((size_t)bh * 64 + (n0q >> 4)) * 1024
            : kfr + ((size_t)bh * 16 + (n0q >> 6)) * 4096;
        #pragma unroll
        for (int mt = 0; mt < 4; ++mt) {
            const int n = n0q + mt * 16 + cl;
            const float* scp = sc + ((size_t)n * 32 + quad * 4) * 2;
            #pragma unroll
            for (int ks = 0; ks < 2; ++ks) {
                const short8 v8 = *(const short8*)&Es[wv][mt * 16 + cl][ks * 32 + quad * 8];
                const short8 p8 = *(const short8*)&Es[wv][mt * 16 + cl][(ks ^ 1) * 32 + quad * 8];
                const float* sp = scp + ks * 32;               // f = ks*16 + quad*4
                const float4 s0 = *(const float4*)sp;
                const float4 s1 = *(const float4*)(sp + 4);
                const float sv[4] = {s0.x, s0.z, s1.x, s1.z};
                const float cv[4] = {s0.y, s0.w, s1.y, s1.w};
                const float sgn = ks ? 1.0f : -1.0f;           // d<32 <=> ks==0
                short8 pk;
                #pragma unroll
                for (int j = 0; j < 8; ++j) {
                    const int f = j >> 1;
                    const float val = b2f((unsigned short)v8[j]);
                    const float par = b2f((unsigned short)p8[j]);
                    pk[j] = (short)f2b((val * cv[f] + sgn * par * sv[f]) * oscale);
                }
                *(short8*)(base + (((size_t)mt * 2 + ks) * 64 + lane) * 8) = pk;
            }
        }
    }
}

// ---------------- Kernel 4: MFMA flash attention, 32 q/wave, safe registers -----------
// 1 wave/block, 32 q-rows (2 qt chains) to halve per-wave K/V L2 traffic vs 16q,
// fragment-order single-segment loads, fixed-shift softmax, XCD swizzle.
// __launch_bounds__(64,2): 256-VGPR budget — no allocator squeeze, no spill.
__global__ __launch_bounds__(64, 2) void attn_mfma_kernel(
        const unsigned short* __restrict__ qfr, const unsigned short* __restrict__ kfr,
        const unsigned short* __restrict__ vfr, float* __restrict__ out) {
    __shared__ __align__(16) short Plds[2][16][72];   // [qt][q=c][key]

    const int lane = threadIdx.x;
    const int c    = lane & 15;
    const int quad = lane >> 4;
    const int i    = blockIdx.x;
    const int bh   = (i & 7) * 8 + ((i >> 3) & 7);   // XCD swizzle: 8 bh per XCD
    const int q32  = i >> 6;                         // q-tile of 32 rows, [0,32)
    const int b    = bh >> 3, h = bh & 7;

    const unsigned short* qp = qfr + ((size_t)bh * 64 + q32 * 2) * 1024 + lane * 8;
    const unsigned short* kp = kfr + (size_t)bh * 65536 + lane * 8;
    const unsigned short* vp = vfr + (size_t)bh * 65536 + lane * 8;

    short8 qf[2][2];
    #pragma unroll
    for (int qt = 0; qt < 2; ++qt)
        #pragma unroll
        for (int ks = 0; ks < 2; ++ks)
            qf[qt][ks] = *(const short8*)(qp + ((size_t)qt * 2 + ks) * 512);

    floatx4 o_acc[2][4];
    float l_acc[2] = {0.f, 0.f};
    #pragma unroll
    for (int qt = 0; qt < 2; ++qt)
        #pragma unroll
        for (int dt = 0; dt < 4; ++dt) o_acc[qt][dt] = (floatx4){0.f, 0.f, 0.f, 0.f};

    #pragma unroll 1
    for (int kt = 0; kt < 16; ++kt) {
        const unsigned short* kb = kp + (size_t)kt * 4096;
        const unsigned short* vb = vp + (size_t)kt * 4096;
        short8 kf[4][2], vf[4][2];
        #pragma unroll
        for (int mt = 0; mt < 4; ++mt) {
            #pragma unroll
            for (int ks = 0; ks < 2; ++ks) {
                kf[mt][ks] = *(const short8*)(kb + ((size_t)mt * 2 + ks) * 512);
                vf[mt][ks] = *(const short8*)(vb + ((size_t)mt * 2 + ks) * 512);
            }
        }

        // S^T: rows=keys (mt), col=q=c
        floatx4 st[2][4];
        #pragma unroll
        for (int qt = 0; qt < 2; ++qt) {
            #pragma unroll
            for (int mt = 0; mt < 4; ++mt) {
                floatx4 z = (floatx4){0.f, 0.f, 0.f, 0.f};
                z = __builtin_amdgcn_mfma_f32_16x16x32_bf16(kf[mt][0], qf[qt][0], z, 0, 0, 0);
                st[qt][mt] = __builtin_amdgcn_mfma_f32_16x16x32_bf16(kf[mt][1], qf[qt][1], z, 0, 0, 0);
            }
        }

        // fixed-shift exp (P = exp(S-16), shift-invariant); pack to per-wave LDS
        #pragma unroll
        for (int qt = 0; qt < 2; ++qt) {
            #pragma unroll
            for (int mt = 0; mt < 4; ++mt) {
                const float e0 = __expf(st[qt][mt][0] - 16.0f);
                const float e1 = __expf(st[qt][mt][1] - 16.0f);
                const float e2 = __expf(st[qt][mt][2] - 16.0f);
                const float e3 = __expf(st[qt][mt][3] - 16.0f);
                l_acc[qt] += (e0 + e1) + (e2 + e3);
                short4_ pk;
                pk.x = (short)f2b(e0); pk.y = (short)f2b(e1);
                pk.z = (short)f2b(e2); pk.w = (short)f2b(e3);
                *(short4_*)&Plds[qt][c][mt * 16 + quad * 4] = pk;
            }
        }

        // PV: O^T += V^T . P^T
        #pragma unroll
        for (int qt = 0; qt < 2; ++qt) {
            const short8 pf0 = *(const short8*)&Plds[qt][c][quad * 8];
            const short8 pf1 = *(const short8*)&Plds[qt][c][32 + quad * 8];
            #pragma unroll
            for (int dt = 0; dt < 4; ++dt) {
                o_acc[qt][dt] = __builtin_amdgcn_mfma_f32_16x16x32_bf16(vf[dt][0], pf0, o_acc[qt][dt], 0, 0, 0);
                o_acc[qt][dt] = __builtin_amdgcn_mfma_f32_16x16x32_bf16(vf[dt][1], pf1, o_acc[qt][dt], 0, 0, 0);
            }
        }
    }

    #pragma unroll
    for (int qt = 0; qt < 2; ++qt) {
        float l = l_acc[qt];
        l += __shfl_xor(l, 16);
        l += __shfl_xor(l, 32);
        const float inv = 1.0f / l;
        const int qcol = q32 * 32 + qt * 16 + c;
        #pragma unroll
        for (int dt = 0; dt < 4; ++dt) {
            #pragma unroll
            for (int r = 0; r < 4; ++r) {
                const int d = dt * 16 + quad * 4 + r;
                out[((size_t)b * C_DIM + h * HDIM + d) * N_TOK + qcol] = o_acc[qt][dt][r] * inv;
            }
        }
    }
}

extern "C" void kernel_launch(void* const* d_in, const int* in_sizes, int n_in,
                              void* d_out, int out_size, void* d_ws, size_t ws_size,
                              hipStream_t stream) {
    const float* x     = (const float*)d_in[0];
    const float* w     = (const float*)d_in[1];
    const float* bias  = (const float*)d_in[2];
    const float* gamma = (const float*)d_in[3];
    const float* beta  = (const float*)d_in[4];
    float* out = (float*)d_out;

    char* ws = (char*)d_ws;
    float* mu   = (float*)ws;                                   // 32 KB
    float* rsig = (float*)(ws + 32768);                         // 32 KB
    unsigned short* qfr = (unsigned short*)(ws + 65536);        // 8 MB
    unsigned short* kfr = (unsigned short*)(ws + 65536 + 8388608);
    unsigned short* vfr = (unsigned short*)(ws + 65536 + 16777216);
    unsigned short* xnf = (unsigned short*)(ws + 65536 + 25165824);  // 8 MB
    unsigned short* wf  = (unsigned short*)(ws + 65536 + 33554432);  // 1.5 MB
    float* sc           = (float*)(ws + 65536 + 35127296);           // 256 KB

    hipLaunchKernelGGL(prep_kernel, dim3(640), dim3(256), 0, stream, x, w, mu, rsig, sc, wf);
    hipLaunchKernelGGL(xnt_kernel, dim3(8, 16, 8), dim3(256), 0, stream,
                       x, gamma, beta, mu, rsig, xnf);
    hipLaunchKernelGGL(qkv_mfma_kernel, dim3(64, 12), dim3(256), 0, stream,
                       xnf, wf, bias, sc, qfr, kfr, vfr);
    hipLaunchKernelGGL(attn_mfma_kernel, dim3(2048), dim3(64), 0, stream, qfr, kfr, vfr, out);
}

// Round 13
// 141.837 us; speedup vs baseline: 1.0706x; 1.0649x over previous
//
#include <hip/hip_runtime.h>
#include <hip/hip_bf16.h>
#include <math.h>

using bf16 = __hip_bfloat16;
typedef __attribute__((ext_vector_type(8))) short short8;
typedef __attribute__((ext_vector_type(4))) short short4_;
typedef __attribute__((ext_vector_type(4))) float floatx4;

#define C_DIM   512
#define N_TOK   1024
#define NHEAD   8
#define HDIM    64
#define LN_EPSF 1e-5f

// RNE float -> bf16 bits
__device__ __forceinline__ unsigned short f2b(float f) {
    union { float f; unsigned int u; } v; v.f = f;
    unsigned int r = v.u + 0x7FFFu + ((v.u >> 16) & 1u);
    return (unsigned short)(r >> 16);
}
__device__ __forceinline__ float b2f(unsigned short u) {
    union { unsigned int i; float f; } v; v.i = ((unsigned int)u) << 16; return v.f;
}

// ---------------- Kernel 1: prep = LN stats | sincos table | w->frag-order bf16 -------
__global__ __launch_bounds__(256) void prep_kernel(
        const float* __restrict__ x, const float* __restrict__ w,
        float* __restrict__ mu, float* __restrict__ rsig,
        float* __restrict__ sc, unsigned short* __restrict__ wf) {
    __shared__ float red_s[4][64];
    __shared__ float red_q[4][64];
    const int bx = blockIdx.x;
    const int t  = threadIdx.x;
    if (bx < 128) {
        const int rl = t & 63;
        const int cg = t >> 6;
        const int r0 = bx * 64;
        const int b  = r0 >> 10;
        const int n  = (r0 & 1023) + rl;
        const float* xp = x + (size_t)b * C_DIM * N_TOK + n;
        float s = 0.f, q = 0.f;
        #pragma unroll 4
        for (int i = 0; i < 128; ++i) {
            float v = xp[(size_t)(cg * 128 + i) * N_TOK];
            s += v; q += v * v;
        }
        red_s[cg][rl] = s; red_q[cg][rl] = q;
        __syncthreads();
        if (cg == 0) {
            float S = red_s[0][rl] + red_s[1][rl] + red_s[2][rl] + red_s[3][rl];
            float Q = red_q[0][rl] + red_q[1][rl] + red_q[2][rl] + red_q[3][rl];
            float m   = S * (1.0f / C_DIM);
            float var = Q * (1.0f / C_DIM) - m * m;
            mu[r0 + rl]   = m;
            rsig[r0 + rl] = rsqrtf(var + LN_EPSF);
        }
    } else if (bx < 256) {
        const int idx = (bx - 128) * 256 + t;      // n*32 + f
        const int n = idx >> 5, f = idx & 31;
        const float fr = __expf((float)f * (-9.210340371976184f / 32.0f));
        float sv, cv;
        sincosf((float)n * fr, &sv, &cv);
        ((float2*)sc)[idx] = make_float2(sv, cv);
    } else {
        const int id   = (bx - 256) * 256 + t;     // chunk id in [0, 96*16*64)
        const int lane = id & 63;
        const int ksl  = (id >> 6) & 15;
        const int j16  = id >> 10;
        const int c    = lane & 15;
        const int quad = lane >> 4;
        const float* wp = w + (size_t)(j16 * 16 + c) * C_DIM + ksl * 32 + quad * 8;
        const float4 w0 = *(const float4*)(wp);
        const float4 w1 = *(const float4*)(wp + 4);
        short8 pk;
        pk[0] = (short)f2b(w0.x); pk[1] = (short)f2b(w0.y);
        pk[2] = (short)f2b(w0.z); pk[3] = (short)f2b(w0.w);
        pk[4] = (short)f2b(w1.x); pk[5] = (short)f2b(w1.y);
        pk[6] = (short)f2b(w1.z); pk[7] = (short)f2b(w1.w);
        *(short8*)(wf + (size_t)id * 8) = pk;
    }
}

// ---------------- Kernel 2: normalize + transpose -> A-fragment order ----------------
__global__ __launch_bounds__(256) void xnt_kernel(
        const float* __restrict__ x, const float* __restrict__ gamma,
        const float* __restrict__ beta, const float* __restrict__ mu,
        const float* __restrict__ rsig, unsigned short* __restrict__ xnf) {
    __shared__ short Sx[64][72];
    const int t  = threadIdx.x;
    const int c0 = blockIdx.x * 64;
    const int n0 = blockIdx.y * 64;
    const int b  = blockIdx.z;

    const int nq  = t & 15;
    const int crl = t >> 4;
    const int tok = b * N_TOK + n0 + nq * 4;
    const float4 m4 = *(const float4*)(mu + tok);
    const float4 r4 = *(const float4*)(rsig + tok);
    #pragma unroll
    for (int p = 0; p < 4; ++p) {
        const int c = c0 + p * 16 + crl;
        const float g = gamma[c], bt = beta[c];
        const float4 xv = *(const float4*)(x + (size_t)b * C_DIM * N_TOK + (size_t)c * N_TOK + n0 + nq * 4);
        Sx[nq * 4 + 0][p * 16 + crl] = (short)f2b((xv.x - m4.x) * r4.x * g + bt);
        Sx[nq * 4 + 1][p * 16 + crl] = (short)f2b((xv.y - m4.y) * r4.y * g + bt);
        Sx[nq * 4 + 2][p * 16 + crl] = (short)f2b((xv.z - m4.z) * r4.z * g + bt);
        Sx[nq * 4 + 3][p * 16 + crl] = (short)f2b((xv.w - m4.w) * r4.w * g + bt);
    }
    __syncthreads();
    const int wv   = t >> 6;
    const int lane = t & 63;
    const int cfr  = lane & 15;
    const int quad = lane >> 4;
    const int g16  = b * 64 + ((n0 >> 4) + wv);
    #pragma unroll
    for (int ks = 0; ks < 2; ++ks) {
        short8 v = *(const short8*)&Sx[wv * 16 + cfr][ks * 32 + quad * 8];
        *(short8*)(xnf + (((size_t)g16 * 16 + (c0 >> 5) + ks) * 64 + lane) * 8) = v;
    }
}

// ---------------- Kernel 3: QKV MFMA GEMM + bias + RoPE + fragment-order scatter -------
__global__ __launch_bounds__(256) void qkv_mfma_kernel(
        const unsigned short* __restrict__ xnf, const unsigned short* __restrict__ wf,
        const float* __restrict__ bias, const float* __restrict__ sc,
        unsigned short* __restrict__ qfr, unsigned short* __restrict__ kfr,
        unsigned short* __restrict__ vfr) {
    __shared__ short Es[4][64][72];

    const int t    = threadIdx.x;
    const int wv   = t >> 6;
    const int lane = t & 63;
    const int cl   = lane & 15;
    const int quad = lane >> 4;
    const int t0   = blockIdx.x * 128 + (wv & 1) * 64;
    const int j0w  = blockIdx.y * 128 + (wv >> 1) * 64;
    const int which = j0w >> 9;                 // 0=q 1=k 2=v
    const int h     = (j0w >> 6) & 7;
    const int b     = t0 >> 10;
    const int n0q   = t0 & 1023;
    const int bh    = b * NHEAD + h;

    const unsigned short* ap = xnf + (size_t)(t0 >> 4) * 8192 + lane * 8;
    const unsigned short* bp = wf  + (size_t)(j0w >> 4) * 8192 + lane * 8;

    floatx4 acc[4][4];
    #pragma unroll
    for (int i = 0; i < 4; ++i)
        #pragma unroll
        for (int j = 0; j < 4; ++j) acc[i][j] = (floatx4){0.f, 0.f, 0.f, 0.f};

    #pragma unroll 2
    for (int kt = 0; kt < 16; ++kt) {
        short8 af[4], bfr[4];
        #pragma unroll
        for (int tt = 0; tt < 4; ++tt) af[tt]  = *(const short8*)(ap + ((size_t)tt * 16 + kt) * 512);
        #pragma unroll
        for (int jt = 0; jt < 4; ++jt) bfr[jt] = *(const short8*)(bp + ((size_t)jt * 16 + kt) * 512);
        #pragma unroll
        for (int tt = 0; tt < 4; ++tt)
            #pragma unroll
            for (int jt = 0; jt < 4; ++jt)
                acc[tt][jt] = __builtin_amdgcn_mfma_f32_16x16x32_bf16(af[tt], bfr[jt], acc[tt][jt], 0, 0, 0);
    }

    float bj[4];
    #pragma unroll
    for (int jt = 0; jt < 4; ++jt) bj[jt] = bias[j0w + jt * 16 + cl];
    #pragma unroll
    for (int tt = 0; tt < 4; ++tt)
        #pragma unroll
        for (int jt = 0; jt < 4; ++jt)
            #pragma unroll
            for (int r = 0; r < 4; ++r)
                Es[wv][tt * 16 + quad * 4 + r][jt * 16 + cl] = (short)f2b(acc[tt][jt][r] + bj[jt]);
    // same-wave LDS read-after-write: ordered by lgkmcnt (no barrier needed)

    if (which == 2) {
        unsigned short* vfb = vfr + ((size_t)bh * 16 + (n0q >> 6)) * 4096;
        #pragma unroll
        for (int dt = 0; dt < 4; ++dt) {
            #pragma unroll
            for (int ks = 0; ks < 2; ++ks) {
                short8 pk;
                #pragma unroll
                for (int j = 0; j < 8; ++j)
                    pk[j] = Es[wv][ks * 32 + quad * 8 + j][dt * 16 + cl];
                *(short8*)(vfb + (((size_t)dt * 2 + ks) * 64 + lane) * 8) = pk;
            }
        }
    } else {
        const float oscale = (which == 0) ? 0.125f : 1.0f;
        unsigned short* base = (which == 0)
            ? qfr + ((size_t)bh * 64 + (n0q >> 4)) * 1024
            : kfr + ((size_t)bh * 16 + (n0q >> 6)) * 4096;
        #pragma unroll
        for (int mt = 0; mt < 4; ++mt) {
            const int n = n0q + mt * 16 + cl;
            const float* scp = sc + ((size_t)n * 32 + quad * 4) * 2;
            #pragma unroll
            for (int ks = 0; ks < 2; ++ks) {
                const short8 v8 = *(const short8*)&Es[wv][mt * 16 + cl][ks * 32 + quad * 8];
                const short8 p8 = *(const short8*)&Es[wv][mt * 16 + cl][(ks ^ 1) * 32 + quad * 8];
                const float* sp = scp + ks * 32;               // f = ks*16 + quad*4
                const float4 s0 = *(const float4*)sp;
                const float4 s1 = *(const float4*)(sp + 4);
                const float sv[4] = {s0.x, s0.z, s1.x, s1.z};
                const float cv[4] = {s0.y, s0.w, s1.y, s1.w};
                const float sgn = ks ? 1.0f : -1.0f;           // d<32 <=> ks==0
                short8 pk;
                #pragma unroll
                for (int j = 0; j < 8; ++j) {
                    const int f = j >> 1;
                    const float val = b2f((unsigned short)v8[j]);
                    const float par = b2f((unsigned short)p8[j]);
                    pk[j] = (short)f2b((val * cv[f] + sgn * par * sv[f]) * oscale);
                }
                *(short8*)(base + (((size_t)mt * 2 + ks) * 64 + lane) * 8) = pk;
            }
        }
    }
}

// ------- Kernel 4: MFMA flash attention, LDS-shared K/V across 4 waves ----------------
// Block = 256 thr = 4 waves = one (bh, 64 q-rows) tile; wave owns 16 q-rows (R10's
// proven register shape). Per kt the block stages the 16 KB K+V chunk ONCE into LDS
// (register-prefetched one iteration ahead) -> 4x less L2 traffic than R10 while
// keeping per-wave structure identical. Fixed-shift softmax; XCD swizzle.
__global__ __launch_bounds__(256, 3) void attn_mfma_kernel(
        const unsigned short* __restrict__ qfr, const unsigned short* __restrict__ kfr,
        const unsigned short* __restrict__ vfr, float* __restrict__ out) {
    __shared__ __align__(16) short kbuf[4096];        // one kt chunk of K frags (8 KB)
    __shared__ __align__(16) short vbuf[4096];        // one kt chunk of V frags (8 KB)
    __shared__ __align__(16) short Plds[4][16][72];   // per-wave P strip

    const int t    = threadIdx.x;
    const int wv   = t >> 6;
    const int lane = t & 63;
    const int c    = lane & 15;
    const int quad = lane >> 4;
    const int i    = blockIdx.x;
    const int bh   = (i & 7) * 8 + ((i >> 3) & 7);   // XCD swizzle: 8 bh per XCD
    const int q16  = (i >> 6) * 4 + wv;              // wave's 16-q tile, [0,64)
    const int b    = bh >> 3, h = bh & 7;

    const unsigned short* qp   = qfr + ((size_t)bh * 64 + q16) * 1024 + lane * 8;
    const unsigned short* kraw = kfr + (size_t)bh * 65536;
    const unsigned short* vraw = vfr + (size_t)bh * 65536;

    const short8 qf0 = *(const short8*)(qp);
    const short8 qf1 = *(const short8*)(qp + 512);

    floatx4 o_acc[4];
    float l_acc = 0.f;
    #pragma unroll
    for (int dt = 0; dt < 4; ++dt) o_acc[dt] = (floatx4){0.f, 0.f, 0.f, 0.f};

    // staging registers: wave wv covers shorts [wv*1024, wv*1024+1024) of each chunk
    const int soff = wv * 1024 + lane * 8;
    short8 stK[2], stV[2];
    stK[0] = *(const short8*)(kraw + soff);
    stK[1] = *(const short8*)(kraw + soff + 512);
    stV[0] = *(const short8*)(vraw + soff);
    stV[1] = *(const short8*)(vraw + soff + 512);

    #pragma unroll 1
    for (int kt = 0; kt < 16; ++kt) {
        __syncthreads();   // all waves done reading buf from previous kt
        *(short8*)&kbuf[soff]       = stK[0];
        *(short8*)&kbuf[soff + 512] = stK[1];
        *(short8*)&vbuf[soff]       = stV[0];
        *(short8*)&vbuf[soff + 512] = stV[1];
        if (kt < 15) {     // issue next chunk's global loads; consumed next iteration
            const unsigned short* kc = kraw + (size_t)(kt + 1) * 4096;
            const unsigned short* vc = vraw + (size_t)(kt + 1) * 4096;
            stK[0] = *(const short8*)(kc + soff);
            stK[1] = *(const short8*)(kc + soff + 512);
            stV[0] = *(const short8*)(vc + soff);
            stV[1] = *(const short8*)(vc + soff + 512);
        }
        __syncthreads();   // staged chunk visible to all waves

        short8 kf[4][2], vf[4][2];
        #pragma unroll
        for (int mt = 0; mt < 4; ++mt) {
            #pragma unroll
            for (int ks = 0; ks < 2; ++ks) {
                kf[mt][ks] = *(const short8*)&kbuf[((mt * 2 + ks) * 64 + lane) * 8];
                vf[mt][ks] = *(const short8*)&vbuf[((mt * 2 + ks) * 64 + lane) * 8];
            }
        }

        // S^T: rows=keys (mt), col=q=c
        floatx4 st[4];
        #pragma unroll
        for (int mt = 0; mt < 4; ++mt) {
            floatx4 z = (floatx4){0.f, 0.f, 0.f, 0.f};
            z = __builtin_amdgcn_mfma_f32_16x16x32_bf16(kf[mt][0], qf0, z, 0, 0, 0);
            st[mt] = __builtin_amdgcn_mfma_f32_16x16x32_bf16(kf[mt][1], qf1, st[mt] = z, 0, 0, 0);
        }

        // fixed-shift exp (P = exp(S-16), shift-invariant); pack to per-wave LDS strip
        #pragma unroll
        for (int mt = 0; mt < 4; ++mt) {
            const float e0 = __expf(st[mt][0] - 16.0f);
            const float e1 = __expf(st[mt][1] - 16.0f);
            const float e2 = __expf(st[mt][2] - 16.0f);
            const float e3 = __expf(st[mt][3] - 16.0f);
            l_acc += (e0 + e1) + (e2 + e3);
            short4_ pk;
            pk.x = (short)f2b(e0); pk.y = (short)f2b(e1);
            pk.z = (short)f2b(e2); pk.w = (short)f2b(e3);
            *(short4_*)&Plds[wv][c][mt * 16 + quad * 4] = pk;
        }

        // PV: O^T += V^T . P^T   (P round-trip is same-wave, lgkmcnt-ordered)
        const short8 pf0 = *(const short8*)&Plds[wv][c][quad * 8];
        const short8 pf1 = *(const short8*)&Plds[wv][c][32 + quad * 8];
        #pragma unroll
        for (int dt = 0; dt < 4; ++dt) {
            o_acc[dt] = __builtin_amdgcn_mfma_f32_16x16x32_bf16(vf[dt][0], pf0, o_acc[dt], 0, 0, 0);
            o_acc[dt] = __builtin_amdgcn_mfma_f32_16x16x32_bf16(vf[dt][1], pf1, o_acc[dt], 0, 0, 0);
        }
    }

    float l = l_acc;
    l += __shfl_xor(l, 16);
    l += __shfl_xor(l, 32);
    const float inv = 1.0f / l;
    const int qcol = q16 * 16 + c;
    #pragma unroll
    for (int dt = 0; dt < 4; ++dt) {
        #pragma unroll
        for (int r = 0; r < 4; ++r) {
            const int d = dt * 16 + quad * 4 + r;
            out[((size_t)b * C_DIM + h * HDIM + d) * N_TOK + qcol] = o_acc[dt][r] * inv;
        }
    }
}

extern "C" void kernel_launch(void* const* d_in, const int* in_sizes, int n_in,
                              void* d_out, int out_size, void* d_ws, size_t ws_size,
                              hipStream_t stream) {
    const float* x     = (const float*)d_in[0];
    const float* w     = (const float*)d_in[1];
    const float* bias  = (const float*)d_in[2];
    const float* gamma = (const float*)d_in[3];
    const float* beta  = (const float*)d_in[4];
    float* out = (float*)d_out;

    char* ws = (char*)d_ws;
    float* mu   = (float*)ws;                                   // 32 KB
    float* rsig = (float*)(ws + 32768);                         // 32 KB
    unsigned short* qfr = (unsigned short*)(ws + 65536);        // 8 MB
    unsigned short* kfr = (unsigned short*)(ws + 65536 + 8388608);
    unsigned short* vfr = (unsigned short*)(ws + 65536 + 16777216);
    unsigned short* xnf = (unsigned short*)(ws + 65536 + 25165824);  // 8 MB
    unsigned short* wf  = (unsigned short*)(ws + 65536 + 33554432);  // 1.5 MB
    float* sc           = (float*)(ws + 65536 + 35127296);           // 256 KB

    hipLaunchKernelGGL(prep_kernel, dim3(640), dim3(256), 0, stream, x, w, mu, rsig, sc, wf);
    hipLaunchKernelGGL(xnt_kernel, dim3(8, 16, 8), dim3(256), 0, stream,
                       x, gamma, beta, mu, rsig, xnf);
    hipLaunchKernelGGL(qkv_mfma_kernel, dim3(64, 12), dim3(256), 0, stream,
                       xnf, wf, bias, sc, qfr, kfr, vfr);
    hipLaunchKernelGGL(attn_mfma_kernel, dim3(1024), dim3(256), 0, stream, qfr, kfr, vfr, out);
}